// Round 2
// baseline (736.072 us; speedup 1.0000x reference)
//
#include <hip/hip_runtime.h>

#define NVOC 32000
#define MASKID 31999
#define NBINS 1024
#define NTHR 1024
#define LISTCAP 1024

__device__ __forceinline__ int bin_of(float d) {
    // log-space bins over d = logit - max in [-12, 0]
    float bf = (d + 12.0f) * (1024.0f / 12.0f);
    int b = (int)floorf(bf);
    b = b < 0 ? 0 : b;
    return b > (NBINS - 1) ? (NBINS - 1) : b;
}

__device__ __forceinline__ unsigned int fixmass(float e) {
    // e in [0,1] -> fixed point at 2^-32, clamped to u32
    double md = (double)e * 4294967296.0;
    long long m = llrint(md);
    if (m < 0) m = 0;
    if (m > 4294967295LL) m = 4294967295LL;
    return (unsigned int)m;
}

__device__ __forceinline__ unsigned long long shfl_down_ull(unsigned long long v, int off) {
    unsigned int lo = (unsigned int)(v & 0xFFFFFFFFULL);
    unsigned int hi = (unsigned int)(v >> 32);
    lo = __shfl_down(lo, off, 64);
    hi = __shfl_down(hi, off, 64);
    return (((unsigned long long)hi) << 32) | lo;
}

__global__ __launch_bounds__(NTHR, 1) void mdlm_kernel(
    const int* __restrict__ xin,
    const float* __restrict__ logits,
    const float* __restrict__ tin,
    const float* __restrict__ uin,
    float* __restrict__ out,
    int rows)
{
    __shared__ float sL[NVOC];                   // 128000 B: raw logits (never overwritten)
    __shared__ unsigned long long sHist[NBINS];  // 8192 B
    __shared__ unsigned int sList[LISTCAP];      // 4096 B
    __shared__ double sRedD[16];
    __shared__ float sRedF[16];
    __shared__ int sRedI[16];
    __shared__ unsigned long long sRedU[16];
    __shared__ float sZmax, sTT;
    __shared__ int sCnt, sB, sCross, sMaxDrop;
    __shared__ unsigned int sTau;
    __shared__ unsigned long long sZ, sAs, sSfp;

    const int row = blockIdx.x;
    if (row >= rows) return;
    const int tid = threadIdx.x;
    const float* lrow = logits + (size_t)row * NVOC;
    const float* urow = uin + (size_t)row * NVOC;
    float* prow = out + (size_t)rows + (size_t)row * NVOC;

    sHist[tid] = 0ULL;  // NBINS == NTHR
    if (tid == 0) {
        sCnt = 0; sB = -1; sCross = 0; sMaxDrop = -1; sTau = 0xFFFFFFFFu;
        sZ = 0ULL; sSfp = 0ULL; sAs = 0ULL;
        sTT = tin[0];
    }

    // ---- pass A: global -> LDS, row max ----
    float lmax = -3.0e38f;
    for (int v4 = tid; v4 < NVOC / 4; v4 += NTHR) {
        float4 f = ((const float4*)lrow)[v4];
        if (v4 == (MASKID >> 2)) f.w = -1000000.0f;   // MASKID % 4 == 3
        ((float4*)sL)[v4] = f;
        lmax = fmaxf(lmax, fmaxf(fmaxf(f.x, f.y), fmaxf(f.z, f.w)));
    }
    for (int off = 32; off > 0; off >>= 1)
        lmax = fmaxf(lmax, __shfl_down(lmax, off, 64));
    if ((tid & 63) == 0) sRedF[tid >> 6] = lmax;
    __syncthreads();
    if (tid == 0) {
        float m = sRedF[0];
        for (int w = 1; w < NTHR / 64; ++w) m = fmaxf(m, sRedF[w]);
        sZmax = m;
    }
    __syncthreads();
    const float zmax = sZmax;

    // ---- pass B: fixed-point mass histogram + total Z ----
    unsigned long long zloc = 0ULL;
    for (int i = tid; i < NVOC; i += NTHR) {
        float d = sL[i] - zmax;
        float e = expf(d);
        unsigned int m = fixmass(e);
        if (m) atomicAdd(&sHist[bin_of(d)], (unsigned long long)m);
        zloc += m;
    }
    for (int off = 32; off > 0; off >>= 1) zloc += shfl_down_ull(zloc, off);
    if ((tid & 63) == 0) sRedU[tid >> 6] = zloc;
    __syncthreads();
    if (tid == 0) {
        unsigned long long z = 0ULL;
        for (int w = 0; w < NTHR / 64; ++w) z += sRedU[w];
        sZ = z;
    }
    __syncthreads();
    const double T = 0.9 * (double)sZ;

    // ---- pass C: inclusive suffix scan over bins (Hillis-Steele, in place) ----
    for (int dlt = 1; dlt < NBINS; dlt <<= 1) {
        unsigned long long vv = (tid + dlt < NBINS) ? sHist[tid + dlt] : 0ULL;
        __syncthreads();
        sHist[tid] += vv;
        __syncthreads();
    }
    // crossing detection: A_strict(k) < T < A_incl(k)
    {
        unsigned long long Ai = sHist[tid];
        unsigned long long As = (tid + 1 < NBINS) ? sHist[tid + 1] : 0ULL;
        bool dropped = ((double)As >= T);
        bool keptf = ((double)Ai <= T);
        if (dropped) atomicMax(&sMaxDrop, tid);
        if (!dropped && !keptf) { sB = tid; sCross = 1; }
    }
    __syncthreads();
    if (tid == 0) {
        int B = sCross ? sB : sMaxDrop;
        sB = B;
        unsigned long long As;
        if (B < 0) As = sHist[0];                       // nothing dropped: keep all
        else As = (B + 1 < NBINS) ? sHist[B + 1] : 0ULL;
        sAs = As;
        if (!sCross) sSfp = As;                         // kept mass = strict-above B
    }
    __syncthreads();

    const int Bst = sB;
    const int cross = sCross;

    // ---- pass D/E: exact resolution inside the crossing bin ----
    if (cross) {
        for (int i = tid; i < NVOC; i += NTHR) {
            float d = sL[i] - zmax;
            if (bin_of(d) == Bst) {
                unsigned int m = fixmass(expf(d));
                int pos = atomicAdd(&sCnt, 1);
                if (pos < LISTCAP) sList[pos] = m;
            }
        }
        __syncthreads();
        const int K = sCnt < LISTCAP ? sCnt : LISTCAP;
        unsigned long long Gmine = 0ULL;
        unsigned int mj = 0u;
        bool kept = false;
        if (tid < K) {
            mj = sList[tid];
            unsigned long long s = sAs;
            for (int q2 = 0; q2 < K; ++q2) {
                unsigned int mv = sList[q2];
                if (mv >= mj) s += (unsigned long long)mv;
            }
            Gmine = s;
            kept = ((double)s <= T);
            if (kept) atomicMin(&sTau, mj);
        }
        __syncthreads();
        if (tid < K && kept && mj == sTau) sSfp = Gmine;   // kept-mass = G at min kept m
        __syncthreads();
        if (tid == 0 && sTau == 0xFFFFFFFFu) sSfp = sAs;   // no kept token inside bin
        __syncthreads();
    }

    const unsigned int tau = sTau;
    const double invSd = 4294967296.0 / (double)sSfp;   // 1 / S, S in e-units

    // mask_prob in f64, replicating the reference expression order
    const double td = (double)sTT;
    const double mpd = ((1.0 - 1e-3) * (td - 0.05)) / ((1.0 - 1e-3) * td);
    const double omd = 1.0 - mpd;
    const double zmaxd = (double)zmax;

    // ---- pass F: write p_x0, gumbel-ratio argmax (double-precision ratio) ----
    double best = -1.0e300;
    int bidx = 0;
    for (int v4 = tid; v4 < NVOC / 4; v4 += NTHR) {
        float4 uf = ((const float4*)urow)[v4];
        float uu[4] = {uf.x, uf.y, uf.z, uf.w};
        float pp[4];
        const int i0 = v4 * 4;
#pragma unroll
        for (int e4 = 0; e4 < 4; ++e4) {
            const int i = i0 + e4;
            float zf = sL[i];
            float d = zf - zmax;
            float ef = expf(d);
            int b = bin_of(d);
            unsigned int m = fixmass(ef);
            bool kept = (b > Bst) || (cross && b == Bst && m >= tau);
            double ed = exp((double)zf - zmaxd);
            double p = kept ? ed * invSd : 0.0;
            pp[e4] = (float)p;
            double q = (i == MASKID) ? mpd : p * omd;
            double ug = (double)uu[e4] + 1e-10;
            double g = -log(-log(ug) + 1e-10);
            double r = q / (g + 1e-10);
            if (r > best) { best = r; bidx = i; }
        }
        float4 po;
        po.x = pp[0]; po.y = pp[1]; po.z = pp[2]; po.w = pp[3];
        ((float4*)prow)[v4] = po;
    }
    for (int off = 32; off > 0; off >>= 1) {
        double ov = __shfl_down(best, off, 64);
        int oi = __shfl_down(bidx, off, 64);
        if (ov > best || (ov == best && oi < bidx)) { best = ov; bidx = oi; }
    }
    if ((tid & 63) == 0) { sRedD[tid >> 6] = best; sRedI[tid >> 6] = bidx; }
    __syncthreads();
    if (tid == 0) {
        best = sRedD[0]; bidx = sRedI[0];
        for (int w = 1; w < NTHR / 64; ++w) {
            double ov = sRedD[w]; int oi = sRedI[w];
            if (ov > best || (ov == best && oi < bidx)) { best = ov; bidx = oi; }
        }
        int xv = xin[row];
        out[row] = (float)((xv == MASKID) ? bidx : xv);
    }
}

extern "C" void kernel_launch(void* const* d_in, const int* in_sizes, int n_in,
                              void* d_out, int out_size, void* d_ws, size_t ws_size,
                              hipStream_t stream) {
    const int* x = (const int*)d_in[0];
    const float* logits = (const float*)d_in[1];
    const float* t = (const float*)d_in[2];
    const float* u = (const float*)d_in[3];
    float* out = (float*)d_out;
    const int rows = in_sizes[0];  // B*S = 2048
    hipLaunchKernelGGL(mdlm_kernel, dim3(rows), dim3(NTHR), 0, stream,
                       x, logits, t, u, out, rows);
}

// Round 3
// 433.936 us; speedup vs baseline: 1.6963x; 1.6963x over previous
//
#include <hip/hip_runtime.h>

#define NVOC 32000
#define MASKID 31999
#define NBINS 1024
#define NTHR 1024
#define LISTCAP 1024

__device__ __forceinline__ int bin_of(float d) {
    // log-space bins over d = logit - max in [-12, 0]
    float bf = (d + 12.0f) * (1024.0f / 12.0f);
    int b = (int)floorf(bf);
    b = b < 0 ? 0 : b;
    return b > (NBINS - 1) ? (NBINS - 1) : b;
}

__device__ __forceinline__ unsigned int fixmass(float e) {
    // e in [0,1] -> fixed point at 2^-32, clamped to u32
    double md = (double)e * 4294967296.0;
    long long m = llrint(md);
    if (m < 0) m = 0;
    if (m > 4294967295LL) m = 4294967295LL;
    return (unsigned int)m;
}

__device__ __forceinline__ unsigned long long shfl_down_ull(unsigned long long v, int off) {
    unsigned int lo = (unsigned int)(v & 0xFFFFFFFFULL);
    unsigned int hi = (unsigned int)(v >> 32);
    lo = __shfl_down(lo, off, 64);
    hi = __shfl_down(hi, off, 64);
    return (((unsigned long long)hi) << 32) | lo;
}

__global__ __launch_bounds__(NTHR, 1) void mdlm_kernel(
    const int* __restrict__ xin,
    const float* __restrict__ logits,
    const float* __restrict__ tin,
    const float* __restrict__ uin,
    float* __restrict__ out,
    int rows)
{
    __shared__ float sL[NVOC];                   // 128000 B: raw logits (never overwritten)
    __shared__ unsigned long long sHist[NBINS];  // 8192 B
    __shared__ unsigned int sList[LISTCAP];      // 4096 B
    __shared__ double sRedD[16];
    __shared__ float sRedF[16];
    __shared__ int sRedI[16];
    __shared__ unsigned long long sRedU[16];
    __shared__ float sZmax, sTT;
    __shared__ int sCnt, sB, sCross, sMaxDrop;
    __shared__ unsigned int sTau;
    __shared__ unsigned long long sZ, sAs, sSfp;

    const int row = blockIdx.x;
    if (row >= rows) return;
    const int tid = threadIdx.x;
    const float* lrow = logits + (size_t)row * NVOC;
    const float* urow = uin + (size_t)row * NVOC;
    float* prow = out + (size_t)rows + (size_t)row * NVOC;

    sHist[tid] = 0ULL;  // NBINS == NTHR
    if (tid == 0) {
        sCnt = 0; sB = -1; sCross = 0; sMaxDrop = -1; sTau = 0xFFFFFFFFu;
        sZ = 0ULL; sSfp = 0ULL; sAs = 0ULL;
        sTT = tin[0];
    }

    // ---- pass A: global -> LDS, row max ----
    float lmax = -3.0e38f;
    for (int v4 = tid; v4 < NVOC / 4; v4 += NTHR) {
        float4 f = ((const float4*)lrow)[v4];
        if (v4 == (MASKID >> 2)) f.w = -1000000.0f;   // MASKID % 4 == 3
        ((float4*)sL)[v4] = f;
        lmax = fmaxf(lmax, fmaxf(fmaxf(f.x, f.y), fmaxf(f.z, f.w)));
    }
    for (int off = 32; off > 0; off >>= 1)
        lmax = fmaxf(lmax, __shfl_down(lmax, off, 64));
    if ((tid & 63) == 0) sRedF[tid >> 6] = lmax;
    __syncthreads();
    if (tid == 0) {
        float m = sRedF[0];
        for (int w = 1; w < NTHR / 64; ++w) m = fmaxf(m, sRedF[w]);
        sZmax = m;
    }
    __syncthreads();
    const float zmax = sZmax;

    // ---- pass B: fixed-point mass histogram + total Z ----
    unsigned long long zloc = 0ULL;
    for (int i = tid; i < NVOC; i += NTHR) {
        float d = sL[i] - zmax;
        float e = expf(d);
        unsigned int m = fixmass(e);
        if (m) atomicAdd(&sHist[bin_of(d)], (unsigned long long)m);
        zloc += m;
    }
    for (int off = 32; off > 0; off >>= 1) zloc += shfl_down_ull(zloc, off);
    if ((tid & 63) == 0) sRedU[tid >> 6] = zloc;
    __syncthreads();
    if (tid == 0) {
        unsigned long long z = 0ULL;
        for (int w = 0; w < NTHR / 64; ++w) z += sRedU[w];
        sZ = z;
    }
    __syncthreads();
    const double T = 0.9 * (double)sZ;

    // ---- pass C: inclusive suffix scan over bins (Hillis-Steele, in place) ----
    for (int dlt = 1; dlt < NBINS; dlt <<= 1) {
        unsigned long long vv = (tid + dlt < NBINS) ? sHist[tid + dlt] : 0ULL;
        __syncthreads();
        sHist[tid] += vv;
        __syncthreads();
    }
    // crossing detection: A_strict(k) < T < A_incl(k)
    {
        unsigned long long Ai = sHist[tid];
        unsigned long long As = (tid + 1 < NBINS) ? sHist[tid + 1] : 0ULL;
        bool dropped = ((double)As >= T);
        bool keptf = ((double)Ai <= T);
        if (dropped) atomicMax(&sMaxDrop, tid);
        if (!dropped && !keptf) { sB = tid; sCross = 1; }
    }
    __syncthreads();
    if (tid == 0) {
        int B = sCross ? sB : sMaxDrop;
        sB = B;
        unsigned long long As;
        if (B < 0) As = sHist[0];                       // nothing dropped: keep all
        else As = (B + 1 < NBINS) ? sHist[B + 1] : 0ULL;
        sAs = As;
        if (!sCross) sSfp = As;                         // kept mass = strict-above B
    }
    __syncthreads();

    const int Bst = sB;
    const int cross = sCross;

    // ---- pass D/E: exact resolution inside the crossing bin ----
    if (cross) {
        for (int i = tid; i < NVOC; i += NTHR) {
            float d = sL[i] - zmax;
            if (bin_of(d) == Bst) {
                unsigned int m = fixmass(expf(d));
                int pos = atomicAdd(&sCnt, 1);
                if (pos < LISTCAP) sList[pos] = m;
            }
        }
        __syncthreads();
        const int K = sCnt < LISTCAP ? sCnt : LISTCAP;
        unsigned long long Gmine = 0ULL;
        unsigned int mj = 0u;
        bool kept = false;
        if (tid < K) {
            mj = sList[tid];
            unsigned long long s = sAs;
            for (int q2 = 0; q2 < K; ++q2) {
                unsigned int mv = sList[q2];
                if (mv >= mj) s += (unsigned long long)mv;
            }
            Gmine = s;
            kept = ((double)s <= T);
            if (kept) atomicMin(&sTau, mj);
        }
        __syncthreads();
        if (tid < K && kept && mj == sTau) sSfp = Gmine;   // kept-mass = G at min kept m
        __syncthreads();
        if (tid == 0 && sTau == 0xFFFFFFFFu) sSfp = sAs;   // no kept token inside bin
        __syncthreads();
    }

    const unsigned int tau = sTau;
    const double invSd = 4294967296.0 / (double)sSfp;   // 1 / S, S in e-units
    const float invSf = (float)invSd;

    // mask_prob in f64, replicating the reference expression order
    const double td = (double)sTT;
    const double mpd = ((1.0 - 1e-3) * (td - 0.05)) / ((1.0 - 1e-3) * td);
    const double omd = 1.0 - mpd;
    const float mpf = (float)mpd;
    const float omf = (float)omd;
    const double zmaxd = (double)zmax;

    // ---- pass F: write p_x0 (f32), f32-screen gumbel-ratio, track top-2/thread ----
    float r1 = -3.0e38f, r2 = -3.0e38f;
    int   i1 = 0,        i2 = 0;
    float z1 = 0.0f,     z2 = 0.0f;
    float u1 = 0.0f,     u2 = 0.0f;
    for (int v4 = tid; v4 < NVOC / 4; v4 += NTHR) {
        float4 uf = ((const float4*)urow)[v4];
        float4 zf4 = ((const float4*)sL)[v4];
        float uu[4] = {uf.x, uf.y, uf.z, uf.w};
        float zz[4] = {zf4.x, zf4.y, zf4.z, zf4.w};
        float pp[4];
        const int i0 = v4 * 4;
#pragma unroll
        for (int e4 = 0; e4 < 4; ++e4) {
            const int i = i0 + e4;
            float zf = zz[e4];
            float d = zf - zmax;
            float ef = expf(d);
            int b = bin_of(d);
            unsigned int m = fixmass(ef);
            bool kept = (b > Bst) || (cross && b == Bst && m >= tau);
            float p = kept ? ef * invSf : 0.0f;
            pp[e4] = p;
            float q = (i == MASKID) ? mpf : p * omf;
            float ug = uu[e4] + 1e-10f;
            float l1 = __logf(ug);
            float w = 1e-10f - l1;          // -log(u+1e-10) + 1e-10
            float g = -__logf(w);
            float r = q * __builtin_amdgcn_rcpf(g + 1e-10f);
            if (r > r1) {
                r2 = r1; i2 = i1; z2 = z1; u2 = u1;
                r1 = r;  i1 = i;  z1 = zf; u1 = uu[e4];
            } else if (r > r2) {
                r2 = r;  i2 = i;  z2 = zf; u2 = uu[e4];
            }
        }
        float4 po;
        po.x = pp[0]; po.y = pp[1]; po.z = pp[2]; po.w = pp[3];
        ((float4*)prow)[v4] = po;
    }

    // ---- refine the 2 candidates in f64 (exact round-2 expression) ----
    double best; int bidx;
    {
        float d1 = z1 - zmax;
        float e1 = expf(d1);
        unsigned int m1 = fixmass(e1);
        int b1 = bin_of(d1);
        bool k1 = (b1 > Bst) || (cross && b1 == Bst && m1 >= tau);
        double ed = exp((double)z1 - zmaxd);
        double p = k1 ? ed * invSd : 0.0;
        double q = (i1 == MASKID) ? mpd : p * omd;
        double g = -log(-log((double)u1 + 1e-10) + 1e-10);
        best = q / (g + 1e-10);
        bidx = i1;
    }
    {
        float d2 = z2 - zmax;
        float e2 = expf(d2);
        unsigned int m2 = fixmass(e2);
        int b2 = bin_of(d2);
        bool k2 = (b2 > Bst) || (cross && b2 == Bst && m2 >= tau);
        double ed = exp((double)z2 - zmaxd);
        double p = k2 ? ed * invSd : 0.0;
        double q = (i2 == MASKID) ? mpd : p * omd;
        double g = -log(-log((double)u2 + 1e-10) + 1e-10);
        double rd = q / (g + 1e-10);
        if (rd > best || (rd == best && i2 < bidx)) { best = rd; bidx = i2; }
    }

    for (int off = 32; off > 0; off >>= 1) {
        double ov = __shfl_down(best, off, 64);
        int oi = __shfl_down(bidx, off, 64);
        if (ov > best || (ov == best && oi < bidx)) { best = ov; bidx = oi; }
    }
    if ((tid & 63) == 0) { sRedD[tid >> 6] = best; sRedI[tid >> 6] = bidx; }
    __syncthreads();
    if (tid == 0) {
        best = sRedD[0]; bidx = sRedI[0];
        for (int w = 1; w < NTHR / 64; ++w) {
            double ov = sRedD[w]; int oi = sRedI[w];
            if (ov > best || (ov == best && oi < bidx)) { best = ov; bidx = oi; }
        }
        int xv = xin[row];
        out[row] = (float)((xv == MASKID) ? bidx : xv);
    }
}

extern "C" void kernel_launch(void* const* d_in, const int* in_sizes, int n_in,
                              void* d_out, int out_size, void* d_ws, size_t ws_size,
                              hipStream_t stream) {
    const int* x = (const int*)d_in[0];
    const float* logits = (const float*)d_in[1];
    const float* t = (const float*)d_in[2];
    const float* u = (const float*)d_in[3];
    float* out = (float*)d_out;
    const int rows = in_sizes[0];  // B*S = 2048
    hipLaunchKernelGGL(mdlm_kernel, dim3(rows), dim3(NTHR), 0, stream,
                       x, logits, t, u, out, rows);
}

// Round 4
// 344.182 us; speedup vs baseline: 2.1386x; 1.2608x over previous
//
#include <hip/hip_runtime.h>

#define NVOC 32000
#define MASKID 31999
#define NBINS 1024
#define NTHR 1024
#define LISTCAP 2048

typedef unsigned int u32;
typedef unsigned long long u64;

// log2-spaced bins directly from the f32 bit pattern of e in (0,1]:
// 64 bins per octave, covering e in [2^-18, 1); below -> bin 0, top 2 octaves -> 1023.
// Monotone nondecreasing in e, bit-exact across passes.
__device__ __forceinline__ int bin_e(float e) {
    int v = (int)(__float_as_uint(e) >> 17) - 6976;   // 6976 = (127-18)<<6
    v = v < 0 ? 0 : v;
    return v > (NBINS - 1) ? (NBINS - 1) : v;
}

// e in [0,1] -> fixed-point mass at 2^-32 (f32 arithmetic, monotone in e)
__device__ __forceinline__ u32 fix32(float e) {
    float x = e * 4294967296.0f;
    x = fminf(x, 4294967040.0f);
    return (u32)x;
}

__device__ __forceinline__ u64 shfl_down_u64(u64 v, int off) {
    u32 lo = (u32)(v & 0xFFFFFFFFULL);
    u32 hi = (u32)(v >> 32);
    lo = __shfl_down(lo, off, 64);
    hi = __shfl_down(hi, off, 64);
    return (((u64)hi) << 32) | lo;
}

__global__ __launch_bounds__(NTHR, 1) void mdlm_kernel(
    const int* __restrict__ xin,
    const float* __restrict__ logits,
    const float* __restrict__ tin,
    const float* __restrict__ uin,
    float* __restrict__ out,
    int rows)
{
    __shared__ float sE[NVOC];          // holds logits during A/B, then e = exp(z - zmax)
    __shared__ u64 sHist[NBINS];
    __shared__ u32 sList[LISTCAP];
    __shared__ double sRedD[16];
    __shared__ float sRedF[16];
    __shared__ int sRedI[16];
    __shared__ u64 sRedU[16];
    __shared__ float sZmax, sTT;
    __shared__ int sCnt, sB, sCross, sMaxDrop;
    __shared__ u32 sTau;
    __shared__ u64 sZ, sAs, sSfp;

    const int row = blockIdx.x;
    if (row >= rows) return;
    const int tid = threadIdx.x;
    const float* lrow = logits + (size_t)row * NVOC;
    const float* urow = uin + (size_t)row * NVOC;
    float* prow = out + (size_t)rows + (size_t)row * NVOC;

    sHist[tid] = 0ULL;  // NBINS == NTHR
    if (tid == 0) {
        sCnt = 0; sB = -1; sCross = 0; sMaxDrop = -1; sTau = 0xFFFFFFFFu;
        sZ = 0ULL; sSfp = 0ULL; sAs = 0ULL;
        sTT = tin[0];
    }

    // ---- pass A: global -> LDS (raw logits), row max ----
    float lmax = -3.0e38f;
    for (int v4 = tid; v4 < NVOC / 4; v4 += NTHR) {
        float4 f = ((const float4*)lrow)[v4];
        if (v4 == (MASKID >> 2)) f.w = -1000000.0f;   // MASKID % 4 == 3
        ((float4*)sE)[v4] = f;
        lmax = fmaxf(lmax, fmaxf(fmaxf(f.x, f.y), fmaxf(f.z, f.w)));
    }
    for (int off = 32; off > 0; off >>= 1)
        lmax = fmaxf(lmax, __shfl_down(lmax, off, 64));
    if ((tid & 63) == 0) sRedF[tid >> 6] = lmax;
    __syncthreads();
    if (tid == 0) {
        float m = sRedF[0];
        for (int w = 1; w < NTHR / 64; ++w) m = fmaxf(m, sRedF[w]);
        sZmax = m;
    }
    __syncthreads();
    const float zmax = sZmax;

    // ---- pass B: e = exp(z - zmax) in place; fixed-point mass histogram + Z ----
    u64 zloc = 0ULL;
    for (int i = tid; i < NVOC; i += NTHR) {
        float z = sE[i];
        float e = __expf(z - zmax);
        sE[i] = e;
        u32 m = fix32(e);
        if (m) atomicAdd(&sHist[bin_e(e)], (u64)m);
        zloc += m;
    }
    for (int off = 32; off > 0; off >>= 1) zloc += shfl_down_u64(zloc, off);
    if ((tid & 63) == 0) sRedU[tid >> 6] = zloc;
    __syncthreads();
    if (tid == 0) {
        u64 z = 0ULL;
        for (int w = 0; w < NTHR / 64; ++w) z += sRedU[w];
        sZ = z;
    }
    __syncthreads();
    const double T = 0.9 * (double)sZ;

    // ---- pass C: inclusive suffix scan over bins ----
    for (int dlt = 1; dlt < NBINS; dlt <<= 1) {
        u64 vv = (tid + dlt < NBINS) ? sHist[tid + dlt] : 0ULL;
        __syncthreads();
        sHist[tid] += vv;
        __syncthreads();
    }
    // crossing detection: A_strict(k) < T < A_incl(k)
    {
        u64 Ai = sHist[tid];
        u64 As = (tid + 1 < NBINS) ? sHist[tid + 1] : 0ULL;
        bool dropped = ((double)As >= T);
        bool keptf = ((double)Ai <= T);
        if (dropped) atomicMax(&sMaxDrop, tid);
        if (!dropped && !keptf) { sB = tid; sCross = 1; }
    }
    __syncthreads();
    if (tid == 0) {
        int B = sCross ? sB : sMaxDrop;
        sB = B;
        u64 As;
        if (B < 0) As = sHist[0];                       // nothing dropped: keep all
        else As = (B + 1 < NBINS) ? sHist[B + 1] : 0ULL;
        sAs = As;
        if (!sCross) sSfp = As;                         // kept mass = strict-above B
    }
    __syncthreads();

    const int Bst = sB;
    const int cross = sCross;

    // ---- pass D/E: exact resolution inside the crossing bin ----
    if (cross) {
        for (int i = tid; i < NVOC; i += NTHR) {
            float e = sE[i];
            if (bin_e(e) == Bst) {
                u32 m = fix32(e);
                int pos = atomicAdd(&sCnt, 1);
                if (pos < LISTCAP) sList[pos] = m;
            }
        }
        __syncthreads();
        const int K = sCnt < LISTCAP ? sCnt : LISTCAP;
        for (int jj = tid; jj < K; jj += NTHR) {
            u32 mj = sList[jj];
            u64 s = sAs;
            for (int q2 = 0; q2 < K; ++q2) {
                u32 mv = sList[q2];
                if (mv >= mj) s += (u64)mv;
            }
            if ((double)s <= T) atomicMin(&sTau, mj);   // kept
        }
        __syncthreads();
        if (tid == 0) sSfp = sAs;
        __syncthreads();
        u32 tl = sTau;
        if (tl != 0xFFFFFFFFu) {
            u64 part = 0ULL;
            for (int q2 = tid; q2 < K; q2 += NTHR) {
                u32 mv = sList[q2];
                if (mv >= tl) part += (u64)mv;
            }
            if (part) atomicAdd(&sSfp, part);
        }
        __syncthreads();
    }

    // unified kept threshold: kept <=> fix32(e) >= tauU
    u32 tauU;
    {
        u32 tv = sTau;
        u32 edgefix = 0u;
        if (Bst >= 0) edgefix = fix32(__uint_as_float((u32)(Bst + 1 + 6976) << 17));
        if (cross) tauU = (tv != 0xFFFFFFFFu) ? tv : edgefix;
        else       tauU = (Bst < 0) ? 0u : edgefix;
    }

    const double invSd = 4294967296.0 / (double)sSfp;
    const float invSf = (float)invSd;

    // mask_prob in f64, replicating the reference expression order
    const double td = (double)sTT;
    const double mpd = ((1.0 - 1e-3) * (td - 0.05)) / ((1.0 - 1e-3) * td);
    const double omd = 1.0 - mpd;
    const float mpf = (float)mpd;
    const float omf = (float)omd;

    // ---- pass F: write p_x0 (f32), f32-screen gumbel-ratio, track top-2/thread ----
    float r1 = -3.0e38f, r2 = -3.0e38f;
    int   i1 = 0,        i2 = 0;
    float e1 = 0.0f,     e2 = 0.0f;
    float u1 = 0.0f,     u2 = 0.0f;
    for (int v4 = tid; v4 < NVOC / 4; v4 += NTHR) {
        float4 uf = ((const float4*)urow)[v4];
        float4 ef4 = ((const float4*)sE)[v4];
        float uu[4] = {uf.x, uf.y, uf.z, uf.w};
        float ee[4] = {ef4.x, ef4.y, ef4.z, ef4.w};
        float pp[4];
        const int i0 = v4 * 4;
#pragma unroll
        for (int e4 = 0; e4 < 4; ++e4) {
            const int i = i0 + e4;
            float e = ee[e4];
            bool kept = (fix32(e) >= tauU);
            float p = kept ? e * invSf : 0.0f;
            pp[e4] = p;
            float q = p * omf;                 // MASKID handled after the loop
            float ug = uu[e4] + 1e-10f;
            float l1 = __logf(ug);
            float w = 1e-10f - l1;             // -log(u+1e-10) + 1e-10
            float g = -__logf(w);
            float r = q * __builtin_amdgcn_rcpf(g + 1e-10f);
            if (r > r1) {
                r2 = r1; i2 = i1; e2 = e1; u2 = u1;
                r1 = r;  i1 = i;  e1 = e;  u1 = uu[e4];
            } else if (r > r2) {
                r2 = r;  i2 = i;  e2 = e;  u2 = uu[e4];
            }
        }
        float4 po;
        po.x = pp[0]; po.y = pp[1]; po.z = pp[2]; po.w = pp[3];
        ((float4*)prow)[v4] = po;
    }
    // inject the MASK candidate (q = mask_prob), owned by the thread that processed it
    if (tid == ((MASKID >> 2) & (NTHR - 1))) {
        float um = urow[MASKID];
        float ug = um + 1e-10f;
        float l1 = __logf(ug);
        float w = 1e-10f - l1;
        float g = -__logf(w);
        float rm = mpf * __builtin_amdgcn_rcpf(g + 1e-10f);
        if (rm > r1) {
            r2 = r1; i2 = i1; e2 = e1; u2 = u1;
            r1 = rm; i1 = MASKID; e1 = 0.0f; u1 = um;
        } else if (rm > r2) {
            r2 = rm; i2 = MASKID; e2 = 0.0f; u2 = um;
        }
    }

    // ---- refine the 2 candidates: g in f64 (the precision-critical part) ----
    double best; int bidx;
    {
        double q;
        if (i1 == MASKID) q = mpd;
        else {
            bool k = (fix32(e1) >= tauU);
            q = k ? (double)e1 * invSd * omd : 0.0;
        }
        double g = -log(-log((double)u1 + 1e-10) + 1e-10);
        best = q / (g + 1e-10);
        bidx = i1;
    }
    {
        double q;
        if (i2 == MASKID) q = mpd;
        else {
            bool k = (fix32(e2) >= tauU);
            q = k ? (double)e2 * invSd * omd : 0.0;
        }
        double g = -log(-log((double)u2 + 1e-10) + 1e-10);
        double rd = q / (g + 1e-10);
        if (rd > best || (rd == best && i2 < bidx)) { best = rd; bidx = i2; }
    }

    for (int off = 32; off > 0; off >>= 1) {
        double ov = __shfl_down(best, off, 64);
        int oi = __shfl_down(bidx, off, 64);
        if (ov > best || (ov == best && oi < bidx)) { best = ov; bidx = oi; }
    }
    if ((tid & 63) == 0) { sRedD[tid >> 6] = best; sRedI[tid >> 6] = bidx; }
    __syncthreads();
    if (tid == 0) {
        best = sRedD[0]; bidx = sRedI[0];
        for (int w = 1; w < NTHR / 64; ++w) {
            double ov = sRedD[w]; int oi = sRedI[w];
            if (ov > best || (ov == best && oi < bidx)) { best = ov; bidx = oi; }
        }
        int xv = xin[row];
        out[row] = (float)((xv == MASKID) ? bidx : xv);
    }
}

extern "C" void kernel_launch(void* const* d_in, const int* in_sizes, int n_in,
                              void* d_out, int out_size, void* d_ws, size_t ws_size,
                              hipStream_t stream) {
    const int* x = (const int*)d_in[0];
    const float* logits = (const float*)d_in[1];
    const float* t = (const float*)d_in[2];
    const float* u = (const float*)d_in[3];
    float* out = (float*)d_out;
    const int rows = in_sizes[0];  // B*S = 2048
    hipLaunchKernelGGL(mdlm_kernel, dim3(rows), dim3(NTHR), 0, stream,
                       x, logits, t, u, out, rows);
}

// Round 5
// 265.151 us; speedup vs baseline: 2.7760x; 1.2981x over previous
//
#include <hip/hip_runtime.h>

#define NVOC 32000
#define NV4  (NVOC / 4)
#define MASKID 31999
#define NBINS 1024
#define NTHR 1024
#define LISTCAP 2048

typedef unsigned int u32;
typedef unsigned long long u64;

// log2-spaced bins directly from the f32 bit pattern of e in (0,1]:
// 64 bins per octave; below 2^-18 -> bin 0; top -> 1023. Monotone in e.
__device__ __forceinline__ int bin_e(float e) {
    int v = (int)(__float_as_uint(e) >> 17) - 6976;   // 6976 = (127-18)<<6
    v = v < 0 ? 0 : v;
    return v > (NBINS - 1) ? (NBINS - 1) : v;
}

// e in [0,1] -> fixed-point mass at 2^-32 (f32 arithmetic, monotone in e)
__device__ __forceinline__ u32 fix32(float e) {
    float x = e * 4294967296.0f;
    x = fminf(x, 4294967040.0f);
    return (u32)x;
}

__device__ __forceinline__ u64 shfl_down_u64(u64 v, int off) {
    u32 lo = (u32)(v & 0xFFFFFFFFULL);
    u32 hi = (u32)(v >> 32);
    lo = __shfl_down(lo, off, 64);
    hi = __shfl_down(hi, off, 64);
    return (((u64)hi) << 32) | lo;
}

__global__ __launch_bounds__(NTHR, 8) void mdlm_kernel(
    const int* __restrict__ xin,
    const float* __restrict__ logits,
    const float* __restrict__ tin,
    const float* __restrict__ uin,
    float* __restrict__ out,
    int rows)
{
    __shared__ u64 sHist[NBINS];        // 8 KB
    __shared__ u32 sList[LISTCAP];      // 8 KB
    __shared__ double sRedD[16];
    __shared__ float sRedF[16];
    __shared__ int sRedI[16];
    __shared__ u64 sRedU[16];
    __shared__ float sZmax, sTT;
    __shared__ int sCnt, sB, sCross, sMaxDrop;
    __shared__ u32 sTau;
    __shared__ u64 sZ, sAs, sSfp;

    const int row = blockIdx.x;
    if (row >= rows) return;
    const int tid = threadIdx.x;
    const float4* lrow4 = (const float4*)(logits + (size_t)row * NVOC);
    const float* urow = uin + (size_t)row * NVOC;
    float* prow = out + (size_t)rows + (size_t)row * NVOC;

    sHist[tid] = 0ULL;  // NBINS == NTHR
    if (tid == 0) {
        sCnt = 0; sB = -1; sCross = 0; sMaxDrop = -1; sTau = 0xFFFFFFFFu;
        sZ = 0ULL; sSfp = 0ULL; sAs = 0ULL;
        sTT = tin[0];
    }
    __syncthreads();

    // ---- pass A: row max (global read #1) ----
    float lmax = -3.0e38f;
    for (int v4 = tid; v4 < NV4; v4 += NTHR) {
        float4 f = lrow4[v4];
        if (v4 == (MASKID >> 2)) f.w = -1000000.0f;   // MASKID % 4 == 3
        lmax = fmaxf(lmax, fmaxf(fmaxf(f.x, f.y), fmaxf(f.z, f.w)));
    }
    for (int off = 32; off > 0; off >>= 1)
        lmax = fmaxf(lmax, __shfl_down(lmax, off, 64));
    if ((tid & 63) == 0) sRedF[tid >> 6] = lmax;
    __syncthreads();
    if (tid == 0) {
        float m = sRedF[0];
        for (int w = 1; w < NTHR / 64; ++w) m = fmaxf(m, sRedF[w]);
        sZmax = m;
    }
    __syncthreads();
    const float zmax = sZmax;

    // ---- pass B: mass histogram + total Z (global read #2) ----
    u64 zloc = 0ULL;
    for (int v4 = tid; v4 < NV4; v4 += NTHR) {
        float4 f = lrow4[v4];
        if (v4 == (MASKID >> 2)) f.w = -1000000.0f;
        float zz[4] = {f.x, f.y, f.z, f.w};
#pragma unroll
        for (int e4 = 0; e4 < 4; ++e4) {
            float e = __expf(zz[e4] - zmax);
            u32 m = fix32(e);
            atomicAdd(&sHist[bin_e(e)], (u64)m);
            zloc += m;
        }
    }
    for (int off = 32; off > 0; off >>= 1) zloc += shfl_down_u64(zloc, off);
    if ((tid & 63) == 0) sRedU[tid >> 6] = zloc;
    __syncthreads();
    if (tid == 0) {
        u64 z = 0ULL;
        for (int w = 0; w < NTHR / 64; ++w) z += sRedU[w];
        sZ = z;
    }
    __syncthreads();
    const double T = 0.9 * (double)sZ;

    // ---- pass C: inclusive suffix scan over bins ----
    for (int dlt = 1; dlt < NBINS; dlt <<= 1) {
        u64 vv = (tid + dlt < NBINS) ? sHist[tid + dlt] : 0ULL;
        __syncthreads();
        sHist[tid] += vv;
        __syncthreads();
    }
    // crossing detection: A_strict(k) < T < A_incl(k)
    {
        u64 Ai = sHist[tid];
        u64 As = (tid + 1 < NBINS) ? sHist[tid + 1] : 0ULL;
        bool dropped = ((double)As >= T);
        bool keptf = ((double)Ai <= T);
        if (dropped) atomicMax(&sMaxDrop, tid);
        if (!dropped && !keptf) { sB = tid; sCross = 1; }
    }
    __syncthreads();
    if (tid == 0) {
        int B = sCross ? sB : sMaxDrop;
        sB = B;
        u64 As;
        if (B < 0) As = sHist[0];                       // nothing dropped: keep all
        else As = (B + 1 < NBINS) ? sHist[B + 1] : 0ULL;
        sAs = As;
        if (!sCross) sSfp = As;                         // kept mass = strict-above B
    }
    __syncthreads();

    const int Bst = sB;
    const int cross = sCross;

    // ---- pass D/E: exact resolution inside the crossing bin (global read #3) ----
    if (cross) {
        for (int v4 = tid; v4 < NV4; v4 += NTHR) {
            float4 f = lrow4[v4];
            if (v4 == (MASKID >> 2)) f.w = -1000000.0f;
            float zz[4] = {f.x, f.y, f.z, f.w};
#pragma unroll
            for (int e4 = 0; e4 < 4; ++e4) {
                float e = __expf(zz[e4] - zmax);
                if (bin_e(e) == Bst) {
                    u32 m = fix32(e);
                    int pos = atomicAdd(&sCnt, 1);
                    if (pos < LISTCAP) sList[pos] = m;
                }
            }
        }
        __syncthreads();
        const int K = sCnt < LISTCAP ? sCnt : LISTCAP;
        for (int jj = tid; jj < K; jj += NTHR) {
            u32 mj = sList[jj];
            u64 s = sAs;
            for (int q2 = 0; q2 < K; ++q2) {
                u32 mv = sList[q2];
                if (mv >= mj) s += (u64)mv;
            }
            if ((double)s <= T) atomicMin(&sTau, mj);   // kept
        }
        __syncthreads();
        if (tid == 0) sSfp = sAs;
        __syncthreads();
        u32 tl = sTau;
        if (tl != 0xFFFFFFFFu) {
            u64 part = 0ULL;
            for (int q2 = tid; q2 < K; q2 += NTHR) {
                u32 mv = sList[q2];
                if (mv >= tl) part += (u64)mv;
            }
            if (part) atomicAdd(&sSfp, part);
        }
        __syncthreads();
    }

    // unified kept threshold: kept <=> fix32(e) >= tauU
    u32 tauU;
    {
        u32 tv = sTau;
        u32 edgefix = 0u;
        if (Bst >= 0) edgefix = fix32(__uint_as_float((u32)(Bst + 1 + 6976) << 17));
        if (cross) tauU = (tv != 0xFFFFFFFFu) ? tv : edgefix;
        else       tauU = (Bst < 0) ? 0u : edgefix;
    }

    const double invSd = 4294967296.0 / (double)sSfp;
    const float invSf = (float)invSd;

    // mask_prob in f64, replicating the reference expression order
    const double td = (double)sTT;
    const double mpd = ((1.0 - 1e-3) * (td - 0.05)) / ((1.0 - 1e-3) * td);
    const double omd = 1.0 - mpd;
    const float mpf = (float)mpd;
    const float omf = (float)omd;

    // ---- pass F: write p_x0, f32-screen gumbel-ratio, top-2/thread (global read #4) ----
    float r1 = -3.0e38f, r2 = -3.0e38f;
    int   i1 = 0,        i2 = 0;
    float e1 = 0.0f,     e2 = 0.0f;
    float u1 = 0.0f,     u2 = 0.0f;
    for (int v4 = tid; v4 < NV4; v4 += NTHR) {
        float4 uf = ((const float4*)urow)[v4];
        float4 f = lrow4[v4];
        if (v4 == (MASKID >> 2)) f.w = -1000000.0f;
        float uu[4] = {uf.x, uf.y, uf.z, uf.w};
        float zz[4] = {f.x, f.y, f.z, f.w};
        float pp[4];
        const int i0 = v4 * 4;
#pragma unroll
        for (int e4 = 0; e4 < 4; ++e4) {
            const int i = i0 + e4;
            float e = __expf(zz[e4] - zmax);
            bool kept = (fix32(e) >= tauU);
            float p = kept ? e * invSf : 0.0f;
            pp[e4] = p;
            float q = p * omf;                 // MASKID handled after the loop
            float ug = uu[e4] + 1e-10f;
            float l1 = __logf(ug);
            float w = 1e-10f - l1;             // -log(u+1e-10) + 1e-10
            float g = -__logf(w);
            float r = q * __builtin_amdgcn_rcpf(g + 1e-10f);
            if (r > r1) {
                r2 = r1; i2 = i1; e2 = e1; u2 = u1;
                r1 = r;  i1 = i;  e1 = e;  u1 = uu[e4];
            } else if (r > r2) {
                r2 = r;  i2 = i;  e2 = e;  u2 = uu[e4];
            }
        }
        float4 po;
        po.x = pp[0]; po.y = pp[1]; po.z = pp[2]; po.w = pp[3];
        ((float4*)prow)[v4] = po;
    }
    // inject the MASK candidate (q = mask_prob), owned by the thread that processed it
    if (tid == ((MASKID >> 2) & (NTHR - 1))) {
        float um = urow[MASKID];
        float ug = um + 1e-10f;
        float l1 = __logf(ug);
        float w = 1e-10f - l1;
        float g = -__logf(w);
        float rm = mpf * __builtin_amdgcn_rcpf(g + 1e-10f);
        if (rm > r1) {
            r2 = r1; i2 = i1; e2 = e1; u2 = u1;
            r1 = rm; i1 = MASKID; e1 = 0.0f; u1 = um;
        } else if (rm > r2) {
            r2 = rm; i2 = MASKID; e2 = 0.0f; u2 = um;
        }
    }

    // ---- refine the 2 candidates: g in f64 (the precision-critical part) ----
    double best; int bidx;
    {
        double q;
        if (i1 == MASKID) q = mpd;
        else {
            bool k = (fix32(e1) >= tauU);
            q = k ? (double)e1 * invSd * omd : 0.0;
        }
        double g = -log(-log((double)u1 + 1e-10) + 1e-10);
        best = q / (g + 1e-10);
        bidx = i1;
    }
    {
        double q;
        if (i2 == MASKID) q = mpd;
        else {
            bool k = (fix32(e2) >= tauU);
            q = k ? (double)e2 * invSd * omd : 0.0;
        }
        double g = -log(-log((double)u2 + 1e-10) + 1e-10);
        double rd = q / (g + 1e-10);
        if (rd > best || (rd == best && i2 < bidx)) { best = rd; bidx = i2; }
    }

    for (int off = 32; off > 0; off >>= 1) {
        double ov = __shfl_down(best, off, 64);
        int oi = __shfl_down(bidx, off, 64);
        if (ov > best || (ov == best && oi < bidx)) { best = ov; bidx = oi; }
    }
    if ((tid & 63) == 0) { sRedD[tid >> 6] = best; sRedI[tid >> 6] = bidx; }
    __syncthreads();
    if (tid == 0) {
        best = sRedD[0]; bidx = sRedI[0];
        for (int w = 1; w < NTHR / 64; ++w) {
            double ov = sRedD[w]; int oi = sRedI[w];
            if (ov > best || (ov == best && oi < bidx)) { best = ov; bidx = oi; }
        }
        int xv = xin[row];
        out[row] = (float)((xv == MASKID) ? bidx : xv);
    }
}

extern "C" void kernel_launch(void* const* d_in, const int* in_sizes, int n_in,
                              void* d_out, int out_size, void* d_ws, size_t ws_size,
                              hipStream_t stream) {
    const int* x = (const int*)d_in[0];
    const float* logits = (const float*)d_in[1];
    const float* t = (const float*)d_in[2];
    const float* u = (const float*)d_in[3];
    float* out = (float*)d_out;
    const int rows = in_sizes[0];  // B*S = 2048
    hipLaunchKernelGGL(mdlm_kernel, dim3(rows), dim3(NTHR), 0, stream,
                       x, logits, t, u, out, rows);
}